// Round 12
// baseline (1529.562 us; speedup 1.0000x reference)
//
#include <hip/hip_runtime.h>
#include <cstdint>
#include <cstddef>

#define MB_   4096
#define NK_   8
#define DM_   1024
#define DT_   128

typedef __bf16 bf16;
typedef __bf16 bf16x8 __attribute__((ext_vector_type(8)));
typedef __bf16 bf16x4 __attribute__((ext_vector_type(4)));
typedef float  f32x4  __attribute__((ext_vector_type(4)));

__device__ __forceinline__ void gload_lds16(const void* g, void* l) {
  __builtin_amdgcn_global_load_lds(
      (__attribute__((address_space(1))) void*)g,
      (__attribute__((address_space(3))) void*)l,
      16, 0, 0);
}

// chunk swizzle: logical 16B-chunk c of row r lives at LDS chunk c ^ hsw(r).
__device__ __forceinline__ int hsw(int r) { return (r ^ (r >> 2)) & 3; }

// ---------------------------------------------------------------------------
// prep: [0,8192) proj_w f32->bf16 | [8192,12288) w_vs transpose |
//       [12288,12416) attns=1.0 | 12416: zero group counters
__global__ void prep_kernel(const float* __restrict__ pw, bf16* __restrict__ pwb,
                            const float* __restrict__ wvs, bf16* __restrict__ wvt,
                            float* __restrict__ out, int* __restrict__ cnt) {
  int b = blockIdx.x;
  int tid = threadIdx.x;
  if (b < 8192) {
    size_t i = ((size_t)b * 256 + tid) * 4;
    float4 f = *(const float4*)&pw[i];
    bf16x4 o = { (bf16)f.x, (bf16)f.y, (bf16)f.z, (bf16)f.w };
    *(bf16x4*)&pwb[i] = o;
  } else if (b < 12288) {
    int o = (b - 8192) * 256 + tid;
    int d = o & 1023;
    int t = (o >> 10) & 127;
    int n = o >> 17;
    wvt[o] = (bf16)wvs[(size_t)n * 131072 + (size_t)d * 128 + t];
  } else if (b < 12416) {
    out[(size_t)33554432 + (size_t)(b - 12288) * 256 + tid] = 1.0f;
  } else {
    if (tid < 256) cnt[tid] = 0;
  }
}

// ---------------------------------------------------------------------------
// GEMM1: v_s[n] = V_n[4096x1024](f32) @ WvT[n][128x1024]^T -> A2 scatter (bf16)
__global__ __launch_bounds__(256, 2) void gemm1_kernel(
    const float* __restrict__ vflat, const bf16* __restrict__ WvT,
    bf16* __restrict__ A2)
{
  __shared__ __align__(16) bf16 As[64 * 32];
  __shared__ __align__(16) bf16 Bs[128 * 32];
  const int tid  = threadIdx.x;
  const int wave = tid >> 6, lane = tid & 63;
  const int wm = wave >> 1, wn = wave & 1;
  const int n  = blockIdx.y;
  const int b0 = blockIdx.x * 64;

  const int r  = tid >> 2;
  const int hr = hsw(r);
  const int cs = (tid & 3) ^ hr;

  const float* ag = vflat + ((size_t)(n * MB_ + b0 + r)) * 1024 + (tid & 3) * 8;
  bf16* awr = As + r * 32 + cs * 8;
  const bf16* bg = WvT + (size_t)n * 131072 + (size_t)r * 1024 + cs * 8;
  char* bsb = (char*)Bs + wave * 1024;

  f32x4 acc[2][4] = {};
  const int krow = lane & 15;
  const int cch  = lane >> 4;
  const int swoff = ((cch ^ hsw(krow)) << 4);

  for (int kt = 0; kt < 32; ++kt) {
    const bf16* bptr = bg + kt * 32;
    gload_lds16(bptr,             bsb);
    gload_lds16(bptr + 64 * 1024, bsb + 4096);
    const float* aptr = ag + kt * 32;
    float4 f0 = *(const float4*)(aptr + 0);
    float4 f1 = *(const float4*)(aptr + 4);
    bf16x8 h0 = { (bf16)f0.x, (bf16)f0.y, (bf16)f0.z, (bf16)f0.w,
                  (bf16)f1.x, (bf16)f1.y, (bf16)f1.z, (bf16)f1.w };
    *(bf16x8*)awr = h0;
    __syncthreads();

    bf16x8 af[2], bfr[4];
    #pragma unroll
    for (int i = 0; i < 2; ++i)
      af[i] = *(const bf16x8*)((const char*)As + (wm * 32 + i * 16 + krow) * 64 + swoff);
    #pragma unroll
    for (int j = 0; j < 4; ++j)
      bfr[j] = *(const bf16x8*)((const char*)Bs + (wn * 64 + j * 16 + krow) * 64 + swoff);
    #pragma unroll
    for (int i = 0; i < 2; ++i)
      #pragma unroll
      for (int j = 0; j < 4; ++j)
        acc[i][j] = __builtin_amdgcn_mfma_f32_16x16x32_bf16(af[i], bfr[j], acc[i][j], 0, 0, 0);
    __syncthreads();
  }

  #pragma unroll
  for (int i = 0; i < 2; ++i) {
    #pragma unroll
    for (int j = 0; j < 4; ++j) {
      int t = wn * 64 + j * 16 + (lane & 15);
      #pragma unroll
      for (int rr = 0; rr < 4; ++rr) {
        int b = b0 + wm * 32 + i * 16 + (lane >> 4) * 4 + rr;
        size_t off = ((size_t)(n * 512 + (b >> 3))) * 1024 + (size_t)(b & 7) * 128 + t;
        A2[off] = (bf16)acc[i][j][rr];
      }
    }
  }
}

// ---------------------------------------------------------------------------
// GEMM2 fused: z = A2 @ PW^T + pb -> zbuf (bf16 ws or f32 d_out region).
// K-loop = round-4 proven 2-phase schedule (4 bufs, 2-deep, vmcnt(4)).
// Tail: per 16-token group, the LAST of its 32 blocks (atomic counter)
// normalizes: x = z + v, wave-per-LN-row butterfly stats, write out.
// Grid map: mt = bid>>5 (16 m-tiles), nt = bid&31 (PW strip nt -> XCD nt&7).
template<bool ZB>
__global__ __launch_bounds__(512, 2) void gemm2f_kernel(
    const bf16* __restrict__ A2, const bf16* __restrict__ PW,
    const float* __restrict__ vres, const float* __restrict__ pb,
    const float* __restrict__ gamma, const float* __restrict__ beta,
    void* __restrict__ zoutp, float* __restrict__ outp, int* __restrict__ cnt)
{
  __shared__ __align__(16) bf16 As[4][8192];  // [buf][256*32]
  __shared__ __align__(16) bf16 Bs[4][8192];
  __shared__ int lastf[16];

  const int tid  = threadIdx.x;
  const int w    = tid >> 6;
  const int lane = tid & 63;
  const int wm   = w >> 2;       // 0..1
  const int wn   = w & 3;        // 0..3

  const int bid = blockIdx.x;    // 0..511
  const int mt  = bid >> 5;      // 0..15
  const int nt  = bid & 31;      // 0..31
  const int m0  = mt * 256;
  const int n0  = nt * 256;

  const int rS = tid >> 2;
  const int cS = (tid & 3) ^ hsw(rS);
  const char* aG0 = (const char*)A2 + (size_t)(m0 + rS) * 2048 + cS * 16;
  const char* aG1 = aG0 + (size_t)128 * 2048;
  const char* bG0 = (const char*)PW + (size_t)(n0 + rS) * 2048 + cS * 16;
  const char* bG1 = bG0 + (size_t)128 * 2048;

  #define STAGE_A(t) { char* d = (char*)As[(t) & 3] + tid * 16;            \
                       gload_lds16(aG0 + (t) * 64, d);                      \
                       gload_lds16(aG1 + (t) * 64, d + 8192); }
  #define STAGE_B(t) { char* d = (char*)Bs[(t) & 3] + tid * 16;            \
                       gload_lds16(bG0 + (t) * 64, d);                      \
                       gload_lds16(bG1 + (t) * 64, d + 8192); }

  STAGE_A(0); STAGE_B(0); STAGE_A(1); STAGE_B(1);
  asm volatile("s_waitcnt vmcnt(4)" ::: "memory");
  __builtin_amdgcn_sched_barrier(0);
  __builtin_amdgcn_s_barrier();

  f32x4 acc[8][4] = {};
  const int fr = lane & 15;
  const int g  = lane >> 4;
  const int swoff = ((g ^ hsw(fr)) << 4);
  const int aRd = (wm * 128 + fr) * 64 + swoff;
  const int bRd = (wn * 64  + fr) * 64 + swoff;

  #pragma unroll 4
  for (int t = 0; t < 32; ++t) {
    const char* pA = (const char*)As[t & 3] + aRd;
    const char* pB = (const char*)Bs[t & 3] + bRd;

    // ---- phase 1 ----
    bf16x8 a[4], b[4];
    #pragma unroll
    for (int m = 0; m < 4; ++m) a[m] = *(const bf16x8*)(pA + m * 1024);
    #pragma unroll
    for (int n = 0; n < 4; ++n) b[n] = *(const bf16x8*)(pB + n * 1024);
    if (t < 30) STAGE_A(t + 2);
    __builtin_amdgcn_s_barrier();
    __builtin_amdgcn_s_setprio(1);
    #pragma unroll
    for (int m = 0; m < 4; ++m)
      #pragma unroll
      for (int n = 0; n < 4; ++n)
        acc[m][n] = __builtin_amdgcn_mfma_f32_16x16x32_bf16(a[m], b[n], acc[m][n], 0, 0, 0);
    __builtin_amdgcn_s_setprio(0);
    __builtin_amdgcn_s_barrier();

    // ---- phase 2 ----
    bf16x8 a2[4];
    #pragma unroll
    for (int m = 0; m < 4; ++m) a2[m] = *(const bf16x8*)(pA + (4 + m) * 1024);
    if (t < 30) STAGE_B(t + 2);
    __builtin_amdgcn_s_barrier();
    __builtin_amdgcn_s_setprio(1);
    #pragma unroll
    for (int m = 0; m < 4; ++m)
      #pragma unroll
      for (int n = 0; n < 4; ++n)
        acc[4 + m][n] = __builtin_amdgcn_mfma_f32_16x16x32_bf16(a2[m], b[n], acc[4 + m][n], 0, 0, 0);
    __builtin_amdgcn_s_setprio(0);
    if (t < 30)       { asm volatile("s_waitcnt vmcnt(4)" ::: "memory"); }
    else if (t == 30) { asm volatile("s_waitcnt vmcnt(0)" ::: "memory"); }
    __builtin_amdgcn_sched_barrier(0);
    __builtin_amdgcn_s_barrier();
  }
  #undef STAGE_A
  #undef STAGE_B

  // ---- epilogue: z = acc + pb -> zbuf ----
  #pragma unroll
  for (int m = 0; m < 8; ++m) {
    #pragma unroll
    for (int n = 0; n < 4; ++n) {
      int nn = n0 + wn * 64 + n * 16 + fr;
      float pbn = pb[nn];
      #pragma unroll
      for (int r = 0; r < 4; ++r) {
        int mm = m0 + wm * 128 + m * 16 + g * 4 + r;
        size_t off = (size_t)mm * 8192 + nn;
        float val = acc[m][n][r] + pbn;
        if (ZB) ((bf16*)zoutp)[off] = (bf16)val;
        else    ((float*)zoutp)[off] = val;
      }
    }
  }

  // ---- group counters: 16 token-groups (16 tokens each) in this m-tile ----
  __threadfence();
  if (tid < 16) {
    int r = __hip_atomic_fetch_add(&cnt[mt * 16 + tid], 1,
                                   __ATOMIC_ACQ_REL, __HIP_MEMORY_SCOPE_AGENT);
    lastf[tid] = (r == 31);
  }
  __syncthreads();

  // gamma/beta per-lane columns (hoisted: same for every LN row)
  for (int gi = 0; gi < 16; ++gi) {
    if (lastf[gi]) {
      __threadfence();
      const int T0 = mt * 256 + gi * 16;     // first token of group
      float4 gv[4], bv[4];
      #pragma unroll
      for (int q = 0; q < 4; ++q) {
        gv[q] = *(const float4*)&gamma[lane * 16 + q * 4];
        bv[q] = *(const float4*)&beta[lane * 16 + q * 4];
      }
      // 128 LN rows; wave w does rows rr*8 + w, rr = 0..15
      for (int rr = 0; rr < 16; ++rr) {
        int lnr = T0 * 8 + rr * 8 + w;
        const size_t rb = (size_t)lnr * 1024 + lane * 16;
        float4 xq[4];
        if (ZB) {
          const bf16* xp = (const bf16*)zoutp + rb;
          bf16x8 z0 = *(const bf16x8*)xp;
          bf16x8 z1 = *(const bf16x8*)(xp + 8);
          xq[0] = make_float4((float)z0[0], (float)z0[1], (float)z0[2], (float)z0[3]);
          xq[1] = make_float4((float)z0[4], (float)z0[5], (float)z0[6], (float)z0[7]);
          xq[2] = make_float4((float)z1[0], (float)z1[1], (float)z1[2], (float)z1[3]);
          xq[3] = make_float4((float)z1[4], (float)z1[5], (float)z1[6], (float)z1[7]);
        } else {
          const float* xp = (const float*)zoutp + rb;
          #pragma unroll
          for (int q = 0; q < 4; ++q) xq[q] = *(const float4*)(xp + q * 4);
        }
        float s = 0.0f, ss = 0.0f;
        #pragma unroll
        for (int q = 0; q < 4; ++q) {
          float4 vv = *(const float4*)&vres[rb + q * 4];
          xq[q].x += vv.x; xq[q].y += vv.y; xq[q].z += vv.z; xq[q].w += vv.w;
          s  += xq[q].x + xq[q].y + xq[q].z + xq[q].w;
          ss += xq[q].x * xq[q].x + xq[q].y * xq[q].y
              + xq[q].z * xq[q].z + xq[q].w * xq[q].w;
        }
        #pragma unroll
        for (int msk = 32; msk >= 1; msk >>= 1) {
          s  += __shfl_xor(s,  msk, 64);
          ss += __shfl_xor(ss, msk, 64);
        }
        float mu  = s * (1.0f / 1024.0f);
        float var = (ss - 1024.0f * mu * mu) * (1.0f / 1023.0f);
        var = var < 0.0f ? 0.0f : var;
        float rs = 1.0f / (sqrtf(var) + 1e-3f);
        #pragma unroll
        for (int q = 0; q < 4; ++q) {
          float4 y;
          y.x = (xq[q].x - mu) * rs * gv[q].x + bv[q].x;
          y.y = (xq[q].y - mu) * rs * gv[q].y + bv[q].y;
          y.z = (xq[q].z - mu) * rs * gv[q].z + bv[q].z;
          y.w = (xq[q].w - mu) * rs * gv[q].w + bv[q].w;
          *(float4*)&outp[rb + q * 4] = y;
        }
      }
    }
  }
}

// ---------------------------------------------------------------------------
extern "C" void kernel_launch(void* const* d_in, const int* in_sizes, int n_in,
                              void* d_out, int out_size, void* d_ws, size_t ws_size,
                              hipStream_t stream) {
  const float* v     = (const float*)d_in[2];
  const float* wvs   = (const float*)d_in[5];
  const float* pw    = (const float*)d_in[6];
  const float* pb    = (const float*)d_in[7];
  const float* gamma = (const float*)d_in[8];
  const float* beta  = (const float*)d_in[9];
  float* out = (float*)d_out;

  // ws: PW bf16 16M | WvT bf16 2M | A2 bf16 8M | cnt 64K | z bf16 64M
  const size_t OFF_WVT = 16777216;
  const size_t OFF_A2  = OFF_WVT + 2097152;
  const size_t OFF_CNT = OFF_A2 + 8388608;
  const size_t OFF_Z   = OFF_CNT + 65536;
  const size_t NEED_ZB = OFF_Z + 67108864;

  bf16* PWb = (bf16*)d_ws;
  bf16* WvT = (bf16*)((char*)d_ws + OFF_WVT);
  bf16* A2  = (bf16*)((char*)d_ws + OFF_A2);
  int*  cnt = (int*)((char*)d_ws + OFF_CNT);
  const bool zb = (ws_size >= NEED_ZB);
  void* zbuf = zb ? (void*)((char*)d_ws + OFF_Z) : (void*)out;

  hipLaunchKernelGGL(prep_kernel, dim3(12417), dim3(256), 0, stream,
                     pw, PWb, wvs, WvT, out, cnt);
  hipLaunchKernelGGL(gemm1_kernel, dim3(64, 8), dim3(256), 0, stream, v, WvT, A2);
  if (zb) {
    hipLaunchKernelGGL((gemm2f_kernel<true>),  dim3(512), dim3(512), 0, stream,
                       A2, PWb, v, pb, gamma, beta, zbuf, out, cnt);
  } else {
    hipLaunchKernelGGL((gemm2f_kernel<false>), dim3(512), dim3(512), 0, stream,
                       A2, PWb, v, pb, gamma, beta, zbuf, out, cnt);
  }
}

// Round 13
// 196.690 us; speedup vs baseline: 7.7765x; 7.7765x over previous
//
#include <hip/hip_runtime.h>
#include <cstdint>
#include <cstddef>

#define MB_   4096
#define NK_   8
#define DM_   1024
#define DT_   128

typedef __bf16 bf16;
typedef __bf16 bf16x8 __attribute__((ext_vector_type(8)));
typedef __bf16 bf16x4 __attribute__((ext_vector_type(4)));
typedef float  f32x4  __attribute__((ext_vector_type(4)));

__device__ __forceinline__ void gload_lds16(const void* g, void* l) {
  __builtin_amdgcn_global_load_lds(
      (__attribute__((address_space(1))) void*)g,
      (__attribute__((address_space(3))) void*)l,
      16, 0, 0);
}

// chunk swizzle: logical 16B-chunk c of row r lives at LDS chunk c ^ hsw(r).
__device__ __forceinline__ int hsw(int r) { return (r ^ (r >> 2)) & 3; }

// ---------------------------------------------------------------------------
// merged prep: [0,8192) proj_w f32->bf16 | [8192,12288) w_vs transpose |
//              [12288,12416) attns = 1.0
__global__ void prep_kernel(const float* __restrict__ pw, bf16* __restrict__ pwb,
                            const float* __restrict__ wvs, bf16* __restrict__ wvt,
                            float* __restrict__ out) {
  int b = blockIdx.x;
  int tid = threadIdx.x;
  if (b < 8192) {
    size_t i = ((size_t)b * 256 + tid) * 4;
    float4 f = *(const float4*)&pw[i];
    bf16x4 o = { (bf16)f.x, (bf16)f.y, (bf16)f.z, (bf16)f.w };
    *(bf16x4*)&pwb[i] = o;
  } else if (b < 12288) {
    int o = (b - 8192) * 256 + tid;
    int d = o & 1023;
    int t = (o >> 10) & 127;
    int n = o >> 17;
    wvt[o] = (bf16)wvs[(size_t)n * 131072 + (size_t)d * 128 + t];
  } else {
    out[(size_t)33554432 + (size_t)(b - 12288) * 256 + tid] = 1.0f;
  }
}

// ---------------------------------------------------------------------------
// GEMM1: v_s[n] = V_n[4096x1024](f32) @ WvT[n][128x1024]^T -> A2 scatter (bf16)
__global__ __launch_bounds__(256, 2) void gemm1_kernel(
    const float* __restrict__ vflat, const bf16* __restrict__ WvT,
    bf16* __restrict__ A2)
{
  __shared__ __align__(16) bf16 As[64 * 32];
  __shared__ __align__(16) bf16 Bs[128 * 32];
  const int tid  = threadIdx.x;
  const int wave = tid >> 6, lane = tid & 63;
  const int wm = wave >> 1, wn = wave & 1;
  const int n  = blockIdx.y;
  const int b0 = blockIdx.x * 64;

  const int r  = tid >> 2;
  const int hr = hsw(r);
  const int cs = (tid & 3) ^ hr;

  const float* ag = vflat + ((size_t)(n * MB_ + b0 + r)) * 1024 + (tid & 3) * 8;
  bf16* awr = As + r * 32 + cs * 8;
  const bf16* bg = WvT + (size_t)n * 131072 + (size_t)r * 1024 + cs * 8;
  char* bsb = (char*)Bs + wave * 1024;

  f32x4 acc[2][4] = {};
  const int krow = lane & 15;
  const int cch  = lane >> 4;
  const int swoff = ((cch ^ hsw(krow)) << 4);

  for (int kt = 0; kt < 32; ++kt) {
    const bf16* bptr = bg + kt * 32;
    gload_lds16(bptr,             bsb);
    gload_lds16(bptr + 64 * 1024, bsb + 4096);
    const float* aptr = ag + kt * 32;
    float4 f0 = *(const float4*)(aptr + 0);
    float4 f1 = *(const float4*)(aptr + 4);
    bf16x8 h0 = { (bf16)f0.x, (bf16)f0.y, (bf16)f0.z, (bf16)f0.w,
                  (bf16)f1.x, (bf16)f1.y, (bf16)f1.z, (bf16)f1.w };
    *(bf16x8*)awr = h0;
    __syncthreads();

    bf16x8 af[2], bfr[4];
    #pragma unroll
    for (int i = 0; i < 2; ++i)
      af[i] = *(const bf16x8*)((const char*)As + (wm * 32 + i * 16 + krow) * 64 + swoff);
    #pragma unroll
    for (int j = 0; j < 4; ++j)
      bfr[j] = *(const bf16x8*)((const char*)Bs + (wn * 64 + j * 16 + krow) * 64 + swoff);
    #pragma unroll
    for (int i = 0; i < 2; ++i)
      #pragma unroll
      for (int j = 0; j < 4; ++j)
        acc[i][j] = __builtin_amdgcn_mfma_f32_16x16x32_bf16(af[i], bfr[j], acc[i][j], 0, 0, 0);
    __syncthreads();
  }

  #pragma unroll
  for (int i = 0; i < 2; ++i) {
    #pragma unroll
    for (int j = 0; j < 4; ++j) {
      int t = wn * 64 + j * 16 + (lane & 15);
      #pragma unroll
      for (int rr = 0; rr < 4; ++rr) {
        int b = b0 + wm * 32 + i * 16 + (lane >> 4) * 4 + rr;
        size_t off = ((size_t)(n * 512 + (b >> 3))) * 1024 + (size_t)(b & 7) * 128 + t;
        A2[off] = (bf16)acc[i][j][rr];
      }
    }
  }
}

// ---------------------------------------------------------------------------
// GEMM2 (best-of-session, round-4 schedule): x = A2 @ PW^T + pb.
// Tile 256x256, BK=32, 4 LDS buffers, 2-deep staging, counted vmcnt(4),
// 2 phases per sub-tile with setprio'd MFMA clusters.
template<bool ZB>
__global__ __launch_bounds__(512, 2) void gemm2p_kernel(
    const bf16* __restrict__ A2, const bf16* __restrict__ PW,
    const float* __restrict__ pb, void* __restrict__ xoutp)
{
  __shared__ __align__(16) bf16 As[4][8192];  // [buf][256*32]
  __shared__ __align__(16) bf16 Bs[4][8192];

  const int tid  = threadIdx.x;
  const int w    = tid >> 6;
  const int lane = tid & 63;
  const int wm   = w >> 2;       // 0..1
  const int wn   = w & 3;        // 0..3

  const int bid   = blockIdx.x;          // 0..511
  const int x     = bid & 7;
  const int local = bid >> 3;            // 0..63
  const int mt    = local & 15;
  const int nt    = x * 4 + (local >> 4);
  const int m0    = mt * 256;
  const int n0    = nt * 256;

  const int rS = tid >> 2;
  const int cS = (tid & 3) ^ hsw(rS);
  const char* aG0 = (const char*)A2 + (size_t)(m0 + rS) * 2048 + cS * 16;
  const char* aG1 = aG0 + (size_t)128 * 2048;
  const char* bG0 = (const char*)PW + (size_t)(n0 + rS) * 2048 + cS * 16;
  const char* bG1 = bG0 + (size_t)128 * 2048;

  #define STAGE_A(t) { char* d = (char*)As[(t) & 3] + tid * 16;            \
                       gload_lds16(aG0 + (t) * 64, d);                      \
                       gload_lds16(aG1 + (t) * 64, d + 8192); }
  #define STAGE_B(t) { char* d = (char*)Bs[(t) & 3] + tid * 16;            \
                       gload_lds16(bG0 + (t) * 64, d);                      \
                       gload_lds16(bG1 + (t) * 64, d + 8192); }

  // prologue: tiles 0 and 1 (8 loads); wait tile 0 (4 in flight)
  STAGE_A(0); STAGE_B(0); STAGE_A(1); STAGE_B(1);
  asm volatile("s_waitcnt vmcnt(4)" ::: "memory");
  __builtin_amdgcn_sched_barrier(0);
  __builtin_amdgcn_s_barrier();

  f32x4 acc[8][4] = {};
  const int fr = lane & 15;
  const int g  = lane >> 4;
  const int swoff = ((g ^ hsw(fr)) << 4);
  const int aRd = (wm * 128 + fr) * 64 + swoff;
  const int bRd = (wn * 64  + fr) * 64 + swoff;

  #pragma unroll 4
  for (int t = 0; t < 32; ++t) {
    const char* pA = (const char*)As[t & 3] + aRd;
    const char* pB = (const char*)Bs[t & 3] + bRd;

    // ---- phase 1: A m0-3 + B reads, stage A(t+2), MFMA Q0 ----
    bf16x8 a[4], b[4];
    #pragma unroll
    for (int m = 0; m < 4; ++m) a[m] = *(const bf16x8*)(pA + m * 1024);
    #pragma unroll
    for (int n = 0; n < 4; ++n) b[n] = *(const bf16x8*)(pB + n * 1024);
    if (t < 30) STAGE_A(t + 2);
    __builtin_amdgcn_s_barrier();
    __builtin_amdgcn_s_setprio(1);
    #pragma unroll
    for (int m = 0; m < 4; ++m)
      #pragma unroll
      for (int n = 0; n < 4; ++n)
        acc[m][n] = __builtin_amdgcn_mfma_f32_16x16x32_bf16(a[m], b[n], acc[m][n], 0, 0, 0);
    __builtin_amdgcn_s_setprio(0);
    __builtin_amdgcn_s_barrier();

    // ---- phase 2: A m4-7 reads, stage B(t+2), counted vmcnt, MFMA Q1 ----
    bf16x8 a2[4];
    #pragma unroll
    for (int m = 0; m < 4; ++m) a2[m] = *(const bf16x8*)(pA + (4 + m) * 1024);
    if (t < 30) STAGE_B(t + 2);
    __builtin_amdgcn_s_barrier();
    __builtin_amdgcn_s_setprio(1);
    #pragma unroll
    for (int m = 0; m < 4; ++m)
      #pragma unroll
      for (int n = 0; n < 4; ++n)
        acc[4 + m][n] = __builtin_amdgcn_mfma_f32_16x16x32_bf16(a2[m], b[n], acc[4 + m][n], 0, 0, 0);
    __builtin_amdgcn_s_setprio(0);
    if (t < 30)       { asm volatile("s_waitcnt vmcnt(4)" ::: "memory"); }
    else if (t == 30) { asm volatile("s_waitcnt vmcnt(0)" ::: "memory"); }
    __builtin_amdgcn_sched_barrier(0);
    __builtin_amdgcn_s_barrier();
  }
  #undef STAGE_A
  #undef STAGE_B

  // epilogue: x = acc + pb -> bf16 ws (or f32 d_out)
  #pragma unroll
  for (int m = 0; m < 8; ++m) {
    #pragma unroll
    for (int n = 0; n < 4; ++n) {
      int nn = n0 + wn * 64 + n * 16 + fr;
      float pbn = pb[nn];
      #pragma unroll
      for (int r = 0; r < 4; ++r) {
        int mm = m0 + wm * 128 + m * 16 + g * 4 + r;
        size_t off = (size_t)mm * 8192 + nn;
        float val = acc[m][n][r] + pbn;
        if (ZB) ((bf16*)xoutp)[off] = (bf16)val;
        else    ((float*)xoutp)[off] = val;
      }
    }
  }
}

// ---------------------------------------------------------------------------
// LN over 1024-wide rows: x = z + v(residual); ddof=1, eps outside sqrt.
template<bool ZB>
__global__ __launch_bounds__(256) void ln_kernel(
    const void* zin, const float* __restrict__ vres,
    const float* __restrict__ gamma, const float* __restrict__ beta,
    float* outp)
{
  __shared__ float red[16];
  const int row = blockIdx.x;
  const int tid = threadIdx.x;
  const size_t base = (size_t)row * 1024 + tid * 4;

  float4 rv = *(const float4*)&vres[base];
  float4 x;
  if (ZB) {
    bf16x4 zb4 = *(const bf16x4*)((const bf16*)zin + base);
    x.x = (float)zb4[0] + rv.x; x.y = (float)zb4[1] + rv.y;
    x.z = (float)zb4[2] + rv.z; x.w = (float)zb4[3] + rv.w;
  } else {
    float4 zf = *(const float4*)((const float*)zin + base);
    x.x = zf.x + rv.x; x.y = zf.y + rv.y; x.z = zf.z + rv.z; x.w = zf.w + rv.w;
  }

  float s  = x.x + x.y + x.z + x.w;
  float ss = x.x * x.x + x.y * x.y + x.z * x.z + x.w * x.w;
  #pragma unroll
  for (int m = 32; m >= 1; m >>= 1) {
    s  += __shfl_xor(s,  m, 64);
    ss += __shfl_xor(ss, m, 64);
  }
  const int wave = tid >> 6, lane = tid & 63;
  if (lane == 0) { red[wave] = s; red[wave + 8] = ss; }
  __syncthreads();
  float S  = red[0] + red[1] + red[2] + red[3];
  float SS = red[8] + red[9] + red[10] + red[11];
  float mu  = S * (1.0f / 1024.0f);
  float var = (SS - 1024.0f * mu * mu) * (1.0f / 1023.0f);
  var = var < 0.0f ? 0.0f : var;
  float rs = 1.0f / (sqrtf(var) + 1e-3f);
  float4 gmv = *(const float4*)&gamma[tid * 4];
  float4 be  = *(const float4*)&beta[tid * 4];
  float4 y;
  y.x = (x.x - mu) * rs * gmv.x + be.x;
  y.y = (x.y - mu) * rs * gmv.y + be.y;
  y.z = (x.z - mu) * rs * gmv.z + be.z;
  y.w = (x.w - mu) * rs * gmv.w + be.w;
  *(float4*)&outp[base] = y;
}

// ---------------------------------------------------------------------------
extern "C" void kernel_launch(void* const* d_in, const int* in_sizes, int n_in,
                              void* d_out, int out_size, void* d_ws, size_t ws_size,
                              hipStream_t stream) {
  const float* v     = (const float*)d_in[2];
  const float* wvs   = (const float*)d_in[5];
  const float* pw    = (const float*)d_in[6];
  const float* pb    = (const float*)d_in[7];
  const float* gamma = (const float*)d_in[8];
  const float* beta  = (const float*)d_in[9];
  float* out = (float*)d_out;

  // ws: PW bf16 16M | WvT bf16 2M | A2 bf16 8M | x bf16 64M
  const size_t OFF_WVT = 16777216;
  const size_t OFF_A2  = OFF_WVT + 2097152;
  const size_t OFF_X   = OFF_A2 + 8388608;
  const size_t NEED_ZB = OFF_X + 67108864;

  bf16* PWb = (bf16*)d_ws;
  bf16* WvT = (bf16*)((char*)d_ws + OFF_WVT);
  bf16* A2  = (bf16*)((char*)d_ws + OFF_A2);
  const bool zb = (ws_size >= NEED_ZB);
  void* xbuf = zb ? (void*)((char*)d_ws + OFF_X) : (void*)out;

  hipLaunchKernelGGL(prep_kernel, dim3(12416), dim3(256), 0, stream, pw, PWb, wvs, WvT, out);
  hipLaunchKernelGGL(gemm1_kernel, dim3(64, 8), dim3(256), 0, stream, v, WvT, A2);
  if (zb) {
    hipLaunchKernelGGL((gemm2p_kernel<true>),  dim3(512), dim3(512), 0, stream, A2, PWb, pb, xbuf);
    hipLaunchKernelGGL((ln_kernel<true>),      dim3(32768), dim3(256), 0, stream, xbuf, v, gamma, beta, out);
  } else {
    hipLaunchKernelGGL((gemm2p_kernel<false>), dim3(512), dim3(512), 0, stream, A2, PWb, pb, xbuf);
    hipLaunchKernelGGL((ln_kernel<false>),     dim3(32768), dim3(256), 0, stream, xbuf, v, gamma, beta, out);
  }
}

// Round 14
// 190.445 us; speedup vs baseline: 8.0315x; 1.0328x over previous
//
#include <hip/hip_runtime.h>
#include <cstdint>
#include <cstddef>

#define MB_   4096
#define NK_   8
#define DM_   1024
#define DT_   128

typedef __bf16 bf16;
typedef __bf16 bf16x8 __attribute__((ext_vector_type(8)));
typedef __bf16 bf16x4 __attribute__((ext_vector_type(4)));
typedef float  f32x4  __attribute__((ext_vector_type(4)));

__device__ __forceinline__ void gload_lds16(const void* g, void* l) {
  __builtin_amdgcn_global_load_lds(
      (__attribute__((address_space(1))) void*)g,
      (__attribute__((address_space(3))) void*)l,
      16, 0, 0);
}

// chunk swizzle: logical 16B-chunk c of row r lives at LDS chunk c ^ hsw(r).
__device__ __forceinline__ int hsw(int r) { return (r ^ (r >> 2)) & 3; }

// ---------------------------------------------------------------------------
// merged prep: [0,8192) proj_w f32->bf16 | [8192,12288) w_vs transpose |
//              [12288,12416) attns = 1.0
__global__ void prep_kernel(const float* __restrict__ pw, bf16* __restrict__ pwb,
                            const float* __restrict__ wvs, bf16* __restrict__ wvt,
                            float* __restrict__ out) {
  int b = blockIdx.x;
  int tid = threadIdx.x;
  if (b < 8192) {
    size_t i = ((size_t)b * 256 + tid) * 4;
    float4 f = *(const float4*)&pw[i];
    bf16x4 o = { (bf16)f.x, (bf16)f.y, (bf16)f.z, (bf16)f.w };
    *(bf16x4*)&pwb[i] = o;
  } else if (b < 12288) {
    int o = (b - 8192) * 256 + tid;
    int d = o & 1023;
    int t = (o >> 10) & 127;
    int n = o >> 17;
    wvt[o] = (bf16)wvs[(size_t)n * 131072 + (size_t)d * 128 + t];
  } else {
    out[(size_t)33554432 + (size_t)(b - 12288) * 256 + tid] = 1.0f;
  }
}

// ---------------------------------------------------------------------------
// GEMM1 pipelined: v_s[n] = V_n[4096x1024](f32) @ WvT[n][128x1024]^T -> A2 (bf16).
// Tile 64x128, BK=32. A: f32 regs (2-deep) -> bf16 ds_write, 2 LDS bufs.
// B: global_load_lds 2-ahead, 3 LDS bufs. Boundary lgkmcnt(0)+vmcnt(4)+barrier
// keeps tile t+2's 4 loads in flight across every barrier (T4/T14).
__global__ __launch_bounds__(256, 2) void gemm1p_kernel(
    const float* __restrict__ vflat, const bf16* __restrict__ WvT,
    bf16* __restrict__ A2)
{
  __shared__ __align__(16) bf16 Ab[2][2048];   // [buf][64*32]  4KB each
  __shared__ __align__(16) bf16 Bb[3][4096];   // [buf][128*32] 8KB each
  const int tid  = threadIdx.x;
  const int wave = tid >> 6, lane = tid & 63;
  const int wm = wave >> 1, wn = wave & 1;
  const int n  = blockIdx.y;
  const int b0 = blockIdx.x * 64;

  const int r  = tid >> 2;
  const int cs = (tid & 3) ^ hsw(r);

  const float* ag = vflat + ((size_t)(n * MB_ + b0 + r)) * 1024 + (tid & 3) * 8;
  const int awOff = r * 32 + cs * 8;           // element offset in Ab[buf]
  const bf16* bg = WvT + (size_t)n * 131072 + (size_t)r * 1024 + cs * 8;
  const int bOff = wave * 1024;                // byte offset of wave's gload dest

  f32x4 ra[2][2];                              // A-reg double buffer

  #define LOADA(t, bi)  { const float* p = ag + (t) * 32;                    \
                          ra[bi][0] = *(const f32x4*)p;                      \
                          ra[bi][1] = *(const f32x4*)(p + 4); }
  #define GLOADB(t, bi) { const bf16* p = bg + (size_t)(t) * 32;             \
                          char* d = (char*)Bb[bi] + bOff;                    \
                          gload_lds16(p, d);                                 \
                          gload_lds16(p + 64 * 1024, d + 4096); }
  #define WRITEA(bi, dst) { f32x4 f0 = ra[bi][0], f1 = ra[bi][1];            \
    bf16x8 h = { (bf16)f0.x, (bf16)f0.y, (bf16)f0.z, (bf16)f0.w,             \
                 (bf16)f1.x, (bf16)f1.y, (bf16)f1.z, (bf16)f1.w };           \
    *(bf16x8*)&Ab[dst][awOff] = h; }

  // prologue: A(0), B(0), A(1), B(1); write A(0); B(0) landed via vmcnt(4)
  LOADA(0, 0); GLOADB(0, 0); LOADA(1, 1); GLOADB(1, 1);
  WRITEA(0, 0);                                // compiler waits ra[0]
  asm volatile("s_waitcnt vmcnt(4)" ::: "memory");  // B(0) done; A(1)+B(1) in flight
  asm volatile("s_waitcnt lgkmcnt(0)" ::: "memory");
  __builtin_amdgcn_s_barrier();
  __builtin_amdgcn_sched_barrier(0);

  f32x4 acc[2][4] = {};
  const int krow = lane & 15;
  const int cch  = lane >> 4;
  const int swoff = ((cch ^ hsw(krow)) << 4);

  #pragma unroll 2
  for (int t = 0; t < 32; ++t) {
    // 1. fragment reads of tile t
    bf16x8 af[2], bfr[4];
    #pragma unroll
    for (int i = 0; i < 2; ++i)
      af[i] = *(const bf16x8*)((const char*)Ab[t & 1] + (wm * 32 + i * 16 + krow) * 64 + swoff);
    #pragma unroll
    for (int j = 0; j < 4; ++j)
      bfr[j] = *(const bf16x8*)((const char*)Bb[t % 3] + (wn * 64 + j * 16 + krow) * 64 + swoff);

    // 2. write A(t+1) (regs -> LDS; compiler inserts the A-reg vmcnt wait)
    if (t < 31) WRITEA((t + 1) & 1, (t + 1) & 1);
    // 3-4. issue tile t+2 loads (stay in flight across the barrier)
    if (t < 30) { LOADA(t + 2, t & 1); GLOADB(t + 2, (t + 2) % 3); }

    // 5. MFMA
    #pragma unroll
    for (int i = 0; i < 2; ++i)
      #pragma unroll
      for (int j = 0; j < 4; ++j)
        acc[i][j] = __builtin_amdgcn_mfma_f32_16x16x32_bf16(af[i], bfr[j], acc[i][j], 0, 0, 0);

    // 6-8. boundary: ds ops done; B(t+1) landed; t+2's 4 loads stay in flight
    if (t < 31) {
      asm volatile("s_waitcnt lgkmcnt(0)" ::: "memory");
      if (t < 30)       { asm volatile("s_waitcnt vmcnt(4)" ::: "memory"); }
      else              { asm volatile("s_waitcnt vmcnt(0)" ::: "memory"); }
      __builtin_amdgcn_s_barrier();
      __builtin_amdgcn_sched_barrier(0);
    }
  }
  #undef LOADA
  #undef GLOADB
  #undef WRITEA

  // epilogue: scatter v_s[n][b][t] -> A2 (torch raw-reshape layout)
  #pragma unroll
  for (int i = 0; i < 2; ++i) {
    #pragma unroll
    for (int j = 0; j < 4; ++j) {
      int t = wn * 64 + j * 16 + (lane & 15);
      #pragma unroll
      for (int rr = 0; rr < 4; ++rr) {
        int b = b0 + wm * 32 + i * 16 + (lane >> 4) * 4 + rr;
        size_t off = ((size_t)(n * 512 + (b >> 3))) * 1024 + (size_t)(b & 7) * 128 + t;
        A2[off] = (bf16)acc[i][j][rr];
      }
    }
  }
}

// ---------------------------------------------------------------------------
// GEMM2 (best-of-session, round-4 schedule): x = A2 @ PW^T + pb.
// Tile 256x256, BK=32, 4 LDS buffers, 2-deep staging, counted vmcnt(4),
// 2 phases per sub-tile with setprio'd MFMA clusters.
template<bool ZB>
__global__ __launch_bounds__(512, 2) void gemm2p_kernel(
    const bf16* __restrict__ A2, const bf16* __restrict__ PW,
    const float* __restrict__ pb, void* __restrict__ xoutp)
{
  __shared__ __align__(16) bf16 As[4][8192];  // [buf][256*32]
  __shared__ __align__(16) bf16 Bs[4][8192];

  const int tid  = threadIdx.x;
  const int w    = tid >> 6;
  const int lane = tid & 63;
  const int wm   = w >> 2;       // 0..1
  const int wn   = w & 3;        // 0..3

  const int bid   = blockIdx.x;          // 0..511
  const int x     = bid & 7;
  const int local = bid >> 3;            // 0..63
  const int mt    = local & 15;
  const int nt    = x * 4 + (local >> 4);
  const int m0    = mt * 256;
  const int n0    = nt * 256;

  const int rS = tid >> 2;
  const int cS = (tid & 3) ^ hsw(rS);
  const char* aG0 = (const char*)A2 + (size_t)(m0 + rS) * 2048 + cS * 16;
  const char* aG1 = aG0 + (size_t)128 * 2048;
  const char* bG0 = (const char*)PW + (size_t)(n0 + rS) * 2048 + cS * 16;
  const char* bG1 = bG0 + (size_t)128 * 2048;

  #define STAGE_A(t) { char* d = (char*)As[(t) & 3] + tid * 16;            \
                       gload_lds16(aG0 + (t) * 64, d);                      \
                       gload_lds16(aG1 + (t) * 64, d + 8192); }
  #define STAGE_B(t) { char* d = (char*)Bs[(t) & 3] + tid * 16;            \
                       gload_lds16(bG0 + (t) * 64, d);                      \
                       gload_lds16(bG1 + (t) * 64, d + 8192); }

  // prologue: tiles 0 and 1 (8 loads); wait tile 0 (4 in flight)
  STAGE_A(0); STAGE_B(0); STAGE_A(1); STAGE_B(1);
  asm volatile("s_waitcnt vmcnt(4)" ::: "memory");
  __builtin_amdgcn_sched_barrier(0);
  __builtin_amdgcn_s_barrier();

  f32x4 acc[8][4] = {};
  const int fr = lane & 15;
  const int g  = lane >> 4;
  const int swoff = ((g ^ hsw(fr)) << 4);
  const int aRd = (wm * 128 + fr) * 64 + swoff;
  const int bRd = (wn * 64  + fr) * 64 + swoff;

  #pragma unroll 4
  for (int t = 0; t < 32; ++t) {
    const char* pA = (const char*)As[t & 3] + aRd;
    const char* pB = (const char*)Bs[t & 3] + bRd;

    // ---- phase 1: A m0-3 + B reads, stage A(t+2), MFMA Q0 ----
    bf16x8 a[4], b[4];
    #pragma unroll
    for (int m = 0; m < 4; ++m) a[m] = *(const bf16x8*)(pA + m * 1024);
    #pragma unroll
    for (int n = 0; n < 4; ++n) b[n] = *(const bf16x8*)(pB + n * 1024);
    if (t < 30) STAGE_A(t + 2);
    __builtin_amdgcn_s_barrier();
    __builtin_amdgcn_s_setprio(1);
    #pragma unroll
    for (int m = 0; m < 4; ++m)
      #pragma unroll
      for (int n = 0; n < 4; ++n)
        acc[m][n] = __builtin_amdgcn_mfma_f32_16x16x32_bf16(a[m], b[n], acc[m][n], 0, 0, 0);
    __builtin_amdgcn_s_setprio(0);
    __builtin_amdgcn_s_barrier();

    // ---- phase 2: A m4-7 reads, stage B(t+2), counted vmcnt, MFMA Q1 ----
    bf16x8 a2[4];
    #pragma unroll
    for (int m = 0; m < 4; ++m) a2[m] = *(const bf16x8*)(pA + (4 + m) * 1024);
    if (t < 30) STAGE_B(t + 2);
    __builtin_amdgcn_s_barrier();
    __builtin_amdgcn_s_setprio(1);
    #pragma unroll
    for (int m = 0; m < 4; ++m)
      #pragma unroll
      for (int n = 0; n < 4; ++n)
        acc[4 + m][n] = __builtin_amdgcn_mfma_f32_16x16x32_bf16(a2[m], b[n], acc[4 + m][n], 0, 0, 0);
    __builtin_amdgcn_s_setprio(0);
    if (t < 30)       { asm volatile("s_waitcnt vmcnt(4)" ::: "memory"); }
    else if (t == 30) { asm volatile("s_waitcnt vmcnt(0)" ::: "memory"); }
    __builtin_amdgcn_sched_barrier(0);
    __builtin_amdgcn_s_barrier();
  }
  #undef STAGE_A
  #undef STAGE_B

  // epilogue: x = acc + pb -> bf16 ws (or f32 d_out)
  #pragma unroll
  for (int m = 0; m < 8; ++m) {
    #pragma unroll
    for (int n = 0; n < 4; ++n) {
      int nn = n0 + wn * 64 + n * 16 + fr;
      float pbn = pb[nn];
      #pragma unroll
      for (int r = 0; r < 4; ++r) {
        int mm = m0 + wm * 128 + m * 16 + g * 4 + r;
        size_t off = (size_t)mm * 8192 + nn;
        float val = acc[m][n][r] + pbn;
        if (ZB) ((bf16*)xoutp)[off] = (bf16)val;
        else    ((float*)xoutp)[off] = val;
      }
    }
  }
}

// ---------------------------------------------------------------------------
// LN over 1024-wide rows: x = z + v(residual); ddof=1, eps outside sqrt.
template<bool ZB>
__global__ __launch_bounds__(256) void ln_kernel(
    const void* zin, const float* __restrict__ vres,
    const float* __restrict__ gamma, const float* __restrict__ beta,
    float* outp)
{
  __shared__ float red[16];
  const int row = blockIdx.x;
  const int tid = threadIdx.x;
  const size_t base = (size_t)row * 1024 + tid * 4;

  float4 rv = *(const float4*)&vres[base];
  float4 x;
  if (ZB) {
    bf16x4 zb4 = *(const bf16x4*)((const bf16*)zin + base);
    x.x = (float)zb4[0] + rv.x; x.y = (float)zb4[1] + rv.y;
    x.z = (float)zb4[2] + rv.z; x.w = (float)zb4[3] + rv.w;
  } else {
    float4 zf = *(const float4*)((const float*)zin + base);
    x.x = zf.x + rv.x; x.y = zf.y + rv.y; x.z = zf.z + rv.z; x.w = zf.w + rv.w;
  }

  float s  = x.x + x.y + x.z + x.w;
  float ss = x.x * x.x + x.y * x.y + x.z * x.z + x.w * x.w;
  #pragma unroll
  for (int m = 32; m >= 1; m >>= 1) {
    s  += __shfl_xor(s,  m, 64);
    ss += __shfl_xor(ss, m, 64);
  }
  const int wave = tid >> 6, lane = tid & 63;
  if (lane == 0) { red[wave] = s; red[wave + 8] = ss; }
  __syncthreads();
  float S  = red[0] + red[1] + red[2] + red[3];
  float SS = red[8] + red[9] + red[10] + red[11];
  float mu  = S * (1.0f / 1024.0f);
  float var = (SS - 1024.0f * mu * mu) * (1.0f / 1023.0f);
  var = var < 0.0f ? 0.0f : var;
  float rs = 1.0f / (sqrtf(var) + 1e-3f);
  float4 gmv = *(const float4*)&gamma[tid * 4];
  float4 be  = *(const float4*)&beta[tid * 4];
  float4 y;
  y.x = (x.x - mu) * rs * gmv.x + be.x;
  y.y = (x.y - mu) * rs * gmv.y + be.y;
  y.z = (x.z - mu) * rs * gmv.z + be.z;
  y.w = (x.w - mu) * rs * gmv.w + be.w;
  *(float4*)&outp[base] = y;
}

// ---------------------------------------------------------------------------
extern "C" void kernel_launch(void* const* d_in, const int* in_sizes, int n_in,
                              void* d_out, int out_size, void* d_ws, size_t ws_size,
                              hipStream_t stream) {
  const float* v     = (const float*)d_in[2];
  const float* wvs   = (const float*)d_in[5];
  const float* pw    = (const float*)d_in[6];
  const float* pb    = (const float*)d_in[7];
  const float* gamma = (const float*)d_in[8];
  const float* beta  = (const float*)d_in[9];
  float* out = (float*)d_out;

  // ws: PW bf16 16M | WvT bf16 2M | A2 bf16 8M | x bf16 64M
  const size_t OFF_WVT = 16777216;
  const size_t OFF_A2  = OFF_WVT + 2097152;
  const size_t OFF_X   = OFF_A2 + 8388608;
  const size_t NEED_ZB = OFF_X + 67108864;

  bf16* PWb = (bf16*)d_ws;
  bf16* WvT = (bf16*)((char*)d_ws + OFF_WVT);
  bf16* A2  = (bf16*)((char*)d_ws + OFF_A2);
  const bool zb = (ws_size >= NEED_ZB);
  void* xbuf = zb ? (void*)((char*)d_ws + OFF_X) : (void*)out;

  hipLaunchKernelGGL(prep_kernel, dim3(12416), dim3(256), 0, stream, pw, PWb, wvs, WvT, out);
  hipLaunchKernelGGL(gemm1p_kernel, dim3(64, 8), dim3(256), 0, stream, v, WvT, A2);
  if (zb) {
    hipLaunchKernelGGL((gemm2p_kernel<true>),  dim3(512), dim3(512), 0, stream, A2, PWb, pb, xbuf);
    hipLaunchKernelGGL((ln_kernel<true>),      dim3(32768), dim3(256), 0, stream, xbuf, v, gamma, beta, out);
  } else {
    hipLaunchKernelGGL((gemm2p_kernel<false>), dim3(512), dim3(512), 0, stream, A2, PWb, pb, xbuf);
    hipLaunchKernelGGL((ln_kernel<false>),     dim3(32768), dim3(256), 0, stream, xbuf, v, gamma, beta, out);
  }
}